// Round 5
// baseline (3769.243 us; speedup 1.0000x reference)
//
#include <hip/hip_runtime.h>

#define NHW 6400
#define CIN 256
#define CIO 128
#define NB 2

#define LOG2E 1.4426950408889634f
#define FSH (-20.0f * LOG2E)   // fixed logit shift, cancels exactly in softmax ratio

// identical exp path in both passes: v_fma_f32 + v_exp_f32
__device__ __forceinline__ float pexp(float f) {
    return __builtin_amdgcn_exp2f(__builtin_fmaf(f, LOG2E, FSH));
}

// ---------------------------------------------------------------------------
// K0: zero the Z accumulator
// ---------------------------------------------------------------------------
__global__ __launch_bounds__(256) void k_zero(float* __restrict__ Zp) {
    const int i = blockIdx.x * 256 + threadIdx.x;
    if (i < NB * NHW) Zp[i] = 0.0f;
}

// ---------------------------------------------------------------------------
// K1: three 1x1-conv projections, all fp32.
// thT[b][ci][n] (theta transposed), ph[b][m][ci], g[b][m][ci].
// ---------------------------------------------------------------------------
__global__ __launch_bounds__(256) void k_proj(
    const float* __restrict__ x,
    const float* __restrict__ gw, const float* __restrict__ gbias,
    const float* __restrict__ tw, const float* __restrict__ tbias,
    const float* __restrict__ pw, const float* __restrict__ pbias,
    float* __restrict__ thT, float* __restrict__ ph, float* __restrict__ g)
{
    __shared__ float xT[16][260];   // [n][c], padded
    const int n0 = blockIdx.x * 16;
    const int b  = blockIdx.y;
    const int t  = threadIdx.x;
    {
        const int nq = t & 3, cq = t >> 2;
        #pragma unroll
        for (int c0 = 0; c0 < 4; ++c0) {
            const int c = c0 * 64 + cq;
            float4 v = *(const float4*)&x[((size_t)b * CIN + c) * NHW + n0 + nq * 4];
            xT[nq*4+0][c] = v.x; xT[nq*4+1][c] = v.y;
            xT[nq*4+2][c] = v.z; xT[nq*4+3][c] = v.w;
        }
    }
    __syncthreads();
    const int ci = t & 127, nh = t >> 7;
    float aG[8], aT[8], aP[8];
    #pragma unroll
    for (int i = 0; i < 8; ++i) { aG[i]=0.f; aT[i]=0.f; aP[i]=0.f; }
    for (int c4 = 0; c4 < 64; ++c4) {
        float4 wg = *(const float4*)&gw[ci*CIN + c4*4];
        float4 wt = *(const float4*)&tw[ci*CIN + c4*4];
        float4 wp = *(const float4*)&pw[ci*CIN + c4*4];
        #pragma unroll
        for (int i = 0; i < 8; ++i) {
            float4 xv = *(const float4*)&xT[nh*8 + i][c4*4];
            aG[i] += wg.x*xv.x + wg.y*xv.y + wg.z*xv.z + wg.w*xv.w;
            aT[i] += wt.x*xv.x + wt.y*xv.y + wt.z*xv.z + wt.w*xv.w;
            aP[i] += wp.x*xv.x + wp.y*xv.y + wp.z*xv.z + wp.w*xv.w;
        }
    }
    const float bg = gbias[ci], bt = tbias[ci], bp = pbias[ci];
    #pragma unroll
    for (int i = 0; i < 8; ++i) {
        const int n = n0 + nh*8 + i;
        thT[((size_t)b * CIO + ci) * NHW + n] = aT[i] + bt;
        ph [((size_t)b * NHW + n) * CIO + ci] = aP[i] + bp;
        g  [((size_t)b * NHW + n) * CIO + ci] = aG[i] + bg;
    }
}

// ---------------------------------------------------------------------------
// K2: Z[m] = sum_n exp(f[n,m]-20), pure fp32 VALU.
// Thread owns n (theta column in 128 VGPRs); loops its m-range; the f fma
// chain is BITWISE-identical to k_pv's. Wave-reduce over 64 n, atomicAdd.
// ---------------------------------------------------------------------------
__global__ __launch_bounds__(256) void k_colsum(
    const float* __restrict__ thT, const float* __restrict__ ph,
    float* __restrict__ Zp)
{
    const int n = blockIdx.x * 256 + threadIdx.x;
    const int b = blockIdx.z;
    const int lane = threadIdx.x & 63;
    float tc[CIO];
    #pragma unroll
    for (int ci = 0; ci < CIO; ++ci)
        tc[ci] = thT[((size_t)b * CIO + ci) * NHW + n];
    const int m_beg = blockIdx.y * (NHW/8), m_end = m_beg + (NHW/8);
    for (int m = m_beg; m < m_end; ++m) {
        const float* pr = ph + ((size_t)b * NHW + m) * CIO;
        float f = 0.0f;
        #pragma unroll
        for (int c4 = 0; c4 < CIO/4; ++c4) {
            float4 pv = *(const float4*)(pr + c4*4);
            f = __builtin_fmaf(tc[c4*4+0], pv.x, f);
            f = __builtin_fmaf(tc[c4*4+1], pv.y, f);
            f = __builtin_fmaf(tc[c4*4+2], pv.z, f);
            f = __builtin_fmaf(tc[c4*4+3], pv.w, f);
        }
        float p = pexp(f);
        p += __shfl_xor(p, 1, 64);  p += __shfl_xor(p, 2, 64);
        p += __shfl_xor(p, 4, 64);  p += __shfl_xor(p, 8, 64);
        p += __shfl_xor(p, 16, 64); p += __shfl_xor(p, 32, 64);
        if (lane == 0) atomicAdd(&Zp[(size_t)b * NHW + m], p);
    }
}

// ---------------------------------------------------------------------------
// K3: y[n][c] = sum_m (exp(f[n,m]-20)/Z[m]) * g[m][c], pure fp32 VALU.
// Same f chain as k_colsum (bitwise) -> softmax exactly consistent.
// Thread owns n and a 64-channel half; yT[b][c][n] output.
// ---------------------------------------------------------------------------
__global__ __launch_bounds__(256) void k_pv(
    const float* __restrict__ thT, const float* __restrict__ ph,
    const float* __restrict__ g, const float* __restrict__ Zp,
    float* __restrict__ yT)
{
    const int n  = blockIdx.x * 256 + threadIdx.x;
    const int mb = blockIdx.y & 7, ch = blockIdx.y >> 3;
    const int b  = blockIdx.z;
    const int c0 = ch * 64;
    float tc[CIO];
    #pragma unroll
    for (int ci = 0; ci < CIO; ++ci)
        tc[ci] = thT[((size_t)b * CIO + ci) * NHW + n];
    float acc[64];
    #pragma unroll
    for (int i = 0; i < 64; ++i) acc[i] = 0.0f;
    const int m_beg = mb * (NHW/8), m_end = m_beg + (NHW/8);
    for (int m = m_beg; m < m_end; ++m) {
        const float* pr = ph + ((size_t)b * NHW + m) * CIO;
        float f = 0.0f;
        #pragma unroll
        for (int c4 = 0; c4 < CIO/4; ++c4) {
            float4 pv = *(const float4*)(pr + c4*4);
            f = __builtin_fmaf(tc[c4*4+0], pv.x, f);
            f = __builtin_fmaf(tc[c4*4+1], pv.y, f);
            f = __builtin_fmaf(tc[c4*4+2], pv.z, f);
            f = __builtin_fmaf(tc[c4*4+3], pv.w, f);
        }
        const float ps = pexp(f) / Zp[(size_t)b * NHW + m];
        const float* gr = g + ((size_t)b * NHW + m) * CIO + c0;
        #pragma unroll
        for (int c4 = 0; c4 < 16; ++c4) {
            float4 gv = *(const float4*)(gr + c4*4);
            acc[c4*4+0] = __builtin_fmaf(ps, gv.x, acc[c4*4+0]);
            acc[c4*4+1] = __builtin_fmaf(ps, gv.y, acc[c4*4+1]);
            acc[c4*4+2] = __builtin_fmaf(ps, gv.z, acc[c4*4+2]);
            acc[c4*4+3] = __builtin_fmaf(ps, gv.w, acc[c4*4+3]);
        }
    }
    // y-halves from the two m-ranges sum via atomics? No: mb splits m, so
    // accumulate partial sums atomically into yT.
    #pragma unroll
    for (int i = 0; i < 64; ++i)
        atomicAdd(&yT[((size_t)b * CIO + c0 + i) * NHW + n], acc[i]);
}

// ---------------------------------------------------------------------------
// K3b: zero yT before k_pv's atomic accumulation
// ---------------------------------------------------------------------------
__global__ __launch_bounds__(256) void k_zeroy(float* __restrict__ yT) {
    const size_t i = (size_t)blockIdx.x * 256 + threadIdx.x;   // grid covers NB*CIO*NHW/4
    float4 z = {0.f, 0.f, 0.f, 0.f};
    *(float4*)&yT[i * 4] = z;
}

// ---------------------------------------------------------------------------
// K4: out[b][co][n] = x + W_b[co] + sum_ci W_w[co][ci] * y[ci][n], fp32.
// ---------------------------------------------------------------------------
__global__ __launch_bounds__(256) void k_out(
    const float* __restrict__ yT, const float* __restrict__ Ww,
    const float* __restrict__ Wbias, const float* __restrict__ x,
    float* __restrict__ out)
{
    const int n   = blockIdx.x * 256 + threadIdx.x;
    const int co0 = blockIdx.y * 32;
    const int b   = blockIdx.z;
    float yc[CIO];
    #pragma unroll
    for (int ci = 0; ci < CIO; ++ci)
        yc[ci] = yT[((size_t)b * CIO + ci) * NHW + n];
    for (int co = co0; co < co0 + 32; ++co) {
        const float* wr = Ww + (size_t)co * CIO;
        float acc = 0.0f;
        #pragma unroll
        for (int c4 = 0; c4 < CIO/4; ++c4) {
            float4 wv = *(const float4*)(wr + c4*4);
            acc = __builtin_fmaf(yc[c4*4+0], wv.x, acc);
            acc = __builtin_fmaf(yc[c4*4+1], wv.y, acc);
            acc = __builtin_fmaf(yc[c4*4+2], wv.z, acc);
            acc = __builtin_fmaf(yc[c4*4+3], wv.w, acc);
        }
        const size_t o = ((size_t)b * CIN + co) * NHW + n;
        out[o] = acc + x[o] + Wbias[co];
    }
}

extern "C" void kernel_launch(void* const* d_in, const int* in_sizes, int n_in,
                              void* d_out, int out_size, void* d_ws, size_t ws_size,
                              hipStream_t stream)
{
    const float* x     = (const float*)d_in[0];
    const float* gw    = (const float*)d_in[1];
    const float* gbias = (const float*)d_in[2];
    const float* tw    = (const float*)d_in[3];
    const float* tbias = (const float*)d_in[4];
    const float* pw    = (const float*)d_in[5];
    const float* pbias = (const float*)d_in[6];
    const float* Ww    = (const float*)d_in[7];
    const float* Wbias = (const float*)d_in[8];

    // thT + ph planes live in d_out (scratch until k_out rewrites it):
    // 2 x 6,553,600 B == out bytes (13,107,200) exactly.
    char* ob = (char*)d_out;
    const size_t SZF = (size_t)NB * NHW * CIO * 4;   // 6,553,600 B
    float* thT = (float*)(ob);
    float* ph  = (float*)(ob + SZF);

    // ws: 13,158,400 B total
    char* ws = (char*)d_ws;
    float* g   = (float*)(ws);               // 6,553,600 B
    float* yT  = (float*)(ws + SZF);         // 6,553,600 B
    float* Zp  = (float*)(ws + 2*SZF);       //    51,200 B
    float* out = (float*)d_out;

    k_zero  <<<dim3(50),        256, 0, stream>>>(Zp);
    k_zeroy <<<dim3(1600),      256, 0, stream>>>(yT);
    k_proj  <<<dim3(400, 2),    256, 0, stream>>>(x, gw, gbias, tw, tbias, pw, pbias,
                                                  thT, ph, g);
    k_colsum<<<dim3(25, 8, 2),  256, 0, stream>>>(thT, ph, Zp);
    k_pv    <<<dim3(25, 16, 2), 256, 0, stream>>>(thT, ph, g, Zp, yT);
    k_out   <<<dim3(25, 8, 2),  256, 0, stream>>>(yT, Ww, Wbias, x, out);
}

// Round 6
// 2500.182 us; speedup vs baseline: 1.5076x; 1.5076x over previous
//
#include <hip/hip_runtime.h>
#include <hip/hip_bf16.h>

#define NHW 6400
#define CIN 256
#define CIO 128
#define NB 2

typedef __bf16 bf16x8 __attribute__((ext_vector_type(8)));
typedef float f32x4 __attribute__((ext_vector_type(4)));

#define LOG2E 1.4426950408889634f
#define FSH (-20.0f * LOG2E)   // fixed logit shift, cancels exactly in softmax ratio

__device__ __forceinline__ unsigned short f2bfu(float x) {
    union { float f; unsigned u; } a; a.f = x;
    unsigned r = (a.u + 0x7fffu + ((a.u >> 16) & 1u)) >> 16;  // RNE
    return (unsigned short)r;
}
__device__ __forceinline__ float bfu2f(unsigned short v) {
    union { unsigned u; float f; } a; a.u = ((unsigned)v) << 16;
    return a.f;
}
__device__ __forceinline__ void splitbf(float v, unsigned short& h, unsigned short& l) {
    unsigned short hh = f2bfu(v);
    h = hh;
    l = f2bfu(v - bfu2f(hh));
}
// identical exp path in both passes: v_fma_f32 + v_exp_f32
__device__ __forceinline__ float pexp(float f) {
    return __builtin_amdgcn_exp2f(__builtin_fmaf(f, LOG2E, FSH));
}

#define MFMA(a, b, c) __builtin_amdgcn_mfma_f32_16x16x32_bf16((a), (b), (c), 0, 0, 0)

// Shared f-tile: f^T for 32 m-rows x 16 n-cols via split-bf16 MFMA.
// A = phi (m rows), B = theta (n cols). BITWISE-identical chain in k_colsum
// and k_attn -> softmax numerator/denominator see identical logits.
// Assumed layouts under test: A/B frag row/col = lane&15, k = (lane>>4)*8+j;
// C/D: col = lane&15 (= n), row = (lane>>4)*4 + reg (= m-offset).
__device__ __forceinline__ void f_tile(
    const unsigned short* __restrict__ ph_hi, const unsigned short* __restrict__ ph_lo,
    size_t a0, size_t a1, const bf16x8* tBh, const bf16x8* tBl,
    f32x4& f0, f32x4& f1)
{
    const f32x4 z4 = {0.f, 0.f, 0.f, 0.f};
    f0 = z4; f1 = z4;
    #pragma unroll
    for (int kk = 0; kk < 4; ++kk) {
        bf16x8 Ah0 = *(const bf16x8*)(ph_hi + a0 + kk*32);
        bf16x8 Al0 = *(const bf16x8*)(ph_lo + a0 + kk*32);
        bf16x8 Ah1 = *(const bf16x8*)(ph_hi + a1 + kk*32);
        bf16x8 Al1 = *(const bf16x8*)(ph_lo + a1 + kk*32);
        f0 = MFMA(Ah0, tBh[kk], f0);
        f0 = MFMA(Ah0, tBl[kk], f0);
        f0 = MFMA(Al0, tBh[kk], f0);
        f1 = MFMA(Ah1, tBh[kk], f1);
        f1 = MFMA(Ah1, tBl[kk], f1);
        f1 = MFMA(Al1, tBh[kk], f1);
    }
}

// ---------------------------------------------------------------------------
// K0: zero the Z accumulator
// ---------------------------------------------------------------------------
__global__ __launch_bounds__(256) void k_zero(float* __restrict__ Zp) {
    const int i = blockIdx.x * 256 + threadIdx.x;
    if (i < NB * NHW) Zp[i] = 0.0f;
}

// ---------------------------------------------------------------------------
// K1: three 1x1-conv projections (fp32 VALU, validated r5). theta/phi ->
// split-bf16 planes [b][n][ci] (carved from d_out); g -> fp32 [b][m][ci].
// ---------------------------------------------------------------------------
__global__ __launch_bounds__(256) void k_proj(
    const float* __restrict__ x,
    const float* __restrict__ gw, const float* __restrict__ gbias,
    const float* __restrict__ tw, const float* __restrict__ tbias,
    const float* __restrict__ pw, const float* __restrict__ pbias,
    unsigned short* __restrict__ th_hi, unsigned short* __restrict__ th_lo,
    unsigned short* __restrict__ ph_hi, unsigned short* __restrict__ ph_lo,
    float* __restrict__ g32)
{
    __shared__ float xT[16][260];   // [n][c], padded
    const int n0 = blockIdx.x * 16;
    const int b  = blockIdx.y;
    const int t  = threadIdx.x;
    {
        const int nq = t & 3, cq = t >> 2;
        #pragma unroll
        for (int c0 = 0; c0 < 4; ++c0) {
            const int c = c0 * 64 + cq;
            float4 v = *(const float4*)&x[((size_t)b * CIN + c) * NHW + n0 + nq * 4];
            xT[nq*4+0][c] = v.x; xT[nq*4+1][c] = v.y;
            xT[nq*4+2][c] = v.z; xT[nq*4+3][c] = v.w;
        }
    }
    __syncthreads();
    const int ci = t & 127, nh = t >> 7;
    float aG[8], aT[8], aP[8];
    #pragma unroll
    for (int i = 0; i < 8; ++i) { aG[i]=0.f; aT[i]=0.f; aP[i]=0.f; }
    for (int c4 = 0; c4 < 64; ++c4) {
        float4 wg = *(const float4*)&gw[ci*CIN + c4*4];
        float4 wt = *(const float4*)&tw[ci*CIN + c4*4];
        float4 wp = *(const float4*)&pw[ci*CIN + c4*4];
        #pragma unroll
        for (int i = 0; i < 8; ++i) {
            float4 xv = *(const float4*)&xT[nh*8 + i][c4*4];
            aG[i] += wg.x*xv.x + wg.y*xv.y + wg.z*xv.z + wg.w*xv.w;
            aT[i] += wt.x*xv.x + wt.y*xv.y + wt.z*xv.z + wt.w*xv.w;
            aP[i] += wp.x*xv.x + wp.y*xv.y + wp.z*xv.z + wp.w*xv.w;
        }
    }
    const float bg = gbias[ci], bt = tbias[ci], bp = pbias[ci];
    #pragma unroll
    for (int i = 0; i < 8; ++i) {
        const size_t o = ((size_t)b * NHW + n0 + nh*8 + i) * CIO + ci;
        unsigned short h, l;
        splitbf(aT[i] + bt, h, l); th_hi[o] = h; th_lo[o] = l;
        splitbf(aP[i] + bp, h, l); ph_hi[o] = h; ph_lo[o] = l;
        g32[o] = aG[i] + bg;
    }
}

// ---------------------------------------------------------------------------
// K2: Z[m] = sum_n exp(f[n,m]-20) via the shared f_tile. Reduce over the
// 16 n (lane&15) with shfl_xor 1/2/4/8; atomicAdd per m.
// ---------------------------------------------------------------------------
__global__ __launch_bounds__(256) void k_colsum(
    const unsigned short* __restrict__ ph_hi, const unsigned short* __restrict__ ph_lo,
    const unsigned short* __restrict__ th_hi, const unsigned short* __restrict__ th_lo,
    float* __restrict__ Zp)
{
    const int n0 = blockIdx.x * 16;
    const int b  = blockIdx.y;
    const int w  = threadIdx.x >> 6;
    const int lane = threadIdx.x & 63;
    const int lm = lane & 15, kg = lane >> 4;
    bf16x8 tBh[4], tBl[4];
    {
        const size_t tb = ((size_t)b * NHW + n0 + lm) * CIO + kg * 8;
        #pragma unroll
        for (int kk = 0; kk < 4; ++kk) {
            tBh[kk] = *(const bf16x8*)(th_hi + tb + kk * 32);
            tBl[kk] = *(const bf16x8*)(th_lo + tb + kk * 32);
        }
    }
    const int m_beg = w * (NHW/4), m_end = m_beg + (NHW/4);
    for (int m0 = m_beg; m0 < m_end; m0 += 32) {
        const size_t a0 = ((size_t)b * NHW + m0 + lm) * CIO + kg * 8;
        const size_t a1 = a0 + (size_t)16 * CIO;
        f32x4 f0, f1;
        f_tile(ph_hi, ph_lo, a0, a1, tBh, tBl, f0, f1);
        #pragma unroll
        for (int j = 0; j < 4; ++j) {
            float v0 = pexp(f0[j]);
            v0 += __shfl_xor(v0, 1, 64); v0 += __shfl_xor(v0, 2, 64);
            v0 += __shfl_xor(v0, 4, 64); v0 += __shfl_xor(v0, 8, 64);
            float v1 = pexp(f1[j]);
            v1 += __shfl_xor(v1, 1, 64); v1 += __shfl_xor(v1, 2, 64);
            v1 += __shfl_xor(v1, 4, 64); v1 += __shfl_xor(v1, 8, 64);
            if ((lane & 15) == 0) {
                atomicAdd(&Zp[(size_t)b * NHW + m0 + kg*4 + j], v0);
                atomicAdd(&Zp[(size_t)b * NHW + m0 + 16 + kg*4 + j], v1);
            }
        }
    }
}

// ---------------------------------------------------------------------------
// K3: y[n][c] = sum_m (exp(f[n,m]-20)/Z[m]) * g[m][c].
// f via the SAME f_tile (bitwise-consistent softmax). PV in fp32 VALU:
// lane (lm=n, kg=channel-quarter) accumulates acc[32]; P values distributed
// from the f-accumulator layout via __shfl (src lane lm+16*((mi>>2)&3),
// reg (mi&3)+4*(mi>>4)). Cross-wave (m-partition) reduce via LDS.
// ---------------------------------------------------------------------------
__global__ __launch_bounds__(256) void k_attn(
    const unsigned short* __restrict__ ph_hi, const unsigned short* __restrict__ ph_lo,
    const unsigned short* __restrict__ th_hi, const unsigned short* __restrict__ th_lo,
    const float* __restrict__ g32, const float* __restrict__ Zp,
    float* __restrict__ yT)
{
    __shared__ float LDSy[4][16][132];
    const int n0 = blockIdx.x * 16;
    const int b  = blockIdx.y;
    const int w  = threadIdx.x >> 6;
    const int lane = threadIdx.x & 63;
    const int lm = lane & 15, kg = lane >> 4;
    bf16x8 tBh[4], tBl[4];
    {
        const size_t tb = ((size_t)b * NHW + n0 + lm) * CIO + kg * 8;
        #pragma unroll
        for (int kk = 0; kk < 4; ++kk) {
            tBh[kk] = *(const bf16x8*)(th_hi + tb + kk * 32);
            tBl[kk] = *(const bf16x8*)(th_lo + tb + kk * 32);
        }
    }
    float acc[32];
    #pragma unroll
    for (int i = 0; i < 32; ++i) acc[i] = 0.0f;

    const int m_beg = w * (NHW/4), m_end = m_beg + (NHW/4);
    for (int m0 = m_beg; m0 < m_end; m0 += 32) {
        const size_t a0 = ((size_t)b * NHW + m0 + lm) * CIO + kg * 8;
        const size_t a1 = a0 + (size_t)16 * CIO;
        f32x4 f0, f1;
        f_tile(ph_hi, ph_lo, a0, a1, tBh, tBl, f0, f1);
        // P with 1/Z folded; lane holds P[n=lm][m0 + kg*4+j (+16)]
        float preg[8];
        const float* zb = Zp + (size_t)b * NHW + m0;
        #pragma unroll
        for (int j = 0; j < 4; ++j) {
            preg[j]     = pexp(f0[j]) / zb[kg*4 + j];
            preg[4 + j] = pexp(f1[j]) / zb[16 + kg*4 + j];
        }
        #pragma unroll
        for (int mi = 0; mi < 32; ++mi) {
            const int kgp = (mi >> 2) & 3;
            const int jp  = (mi & 3) + ((mi >> 4) << 2);
            const float ps = __shfl(preg[jp], lm + 16*kgp, 64);
            const float* gr = g32 + ((size_t)b * NHW + m0 + mi) * CIO + kg * 32;
            #pragma unroll
            for (int c4 = 0; c4 < 8; ++c4) {
                float4 gv = *(const float4*)(gr + c4*4);
                acc[c4*4+0] = __builtin_fmaf(ps, gv.x, acc[c4*4+0]);
                acc[c4*4+1] = __builtin_fmaf(ps, gv.y, acc[c4*4+1]);
                acc[c4*4+2] = __builtin_fmaf(ps, gv.z, acc[c4*4+2]);
                acc[c4*4+3] = __builtin_fmaf(ps, gv.w, acc[c4*4+3]);
            }
        }
    }
    #pragma unroll
    for (int i = 0; i < 32; ++i) LDSy[w][lm][kg*32 + i] = acc[i];
    __syncthreads();
    {
        const int n = threadIdx.x & 15, cg = threadIdx.x >> 4;  // 16 threads x 8 c
        #pragma unroll
        for (int k = 0; k < 8; ++k) {
            const int c = cg*8 + k;
            float s = LDSy[0][n][c] + LDSy[1][n][c] + LDSy[2][n][c] + LDSy[3][n][c];
            yT[((size_t)b * CIO + c) * NHW + n0 + n] = s;
        }
    }
}

// ---------------------------------------------------------------------------
// K3b: W transpose fp32: WT[ci][co] (overlays g32, launched after k_attn)
// ---------------------------------------------------------------------------
__global__ __launch_bounds__(256) void k_wT(
    const float* __restrict__ Ww, float* __restrict__ WT)
{
    const int i = blockIdx.x * 256 + threadIdx.x;   // grid covers 32768
    const int co = i >> 7, ci = i & 127;
    WT[(size_t)ci * CIN + co] = Ww[(size_t)co * CIO + ci];
}

// ---------------------------------------------------------------------------
// K4: out[b][co][n] = x + W_b[co] + sum_ci WT[ci][co] * y[ci][n], fp32 VALU.
// Block = 16 n, 256 threads = 256 co. y tile staged [c][n] in LDS; W reads
// coalesced via WT. acc[16] only -> no spills.
// ---------------------------------------------------------------------------
__global__ __launch_bounds__(256) void k_out(
    const float* __restrict__ yT, const float* __restrict__ WT,
    const float* __restrict__ Wbias, const float* __restrict__ x,
    float* __restrict__ out)
{
    __shared__ float yl[128][20];   // [ci][n], padded to 16B-aligned rows
    const int n0 = blockIdx.x * 16;
    const int b  = blockIdx.y;
    const int t  = threadIdx.x;
    {
        const int c = t >> 1, nh = (t & 1) * 8;
        const float* yp = yT + ((size_t)b * CIO + c) * NHW + n0 + nh;
        float4 v0 = *(const float4*)(yp);
        float4 v1 = *(const float4*)(yp + 4);
        yl[c][nh+0] = v0.x; yl[c][nh+1] = v0.y; yl[c][nh+2] = v0.z; yl[c][nh+3] = v0.w;
        yl[c][nh+4] = v1.x; yl[c][nh+5] = v1.y; yl[c][nh+6] = v1.z; yl[c][nh+7] = v1.w;
    }
    __syncthreads();
    const int co = t;
    float acc[16];
    #pragma unroll
    for (int i = 0; i < 16; ++i) acc[i] = 0.0f;
    for (int ci = 0; ci < CIO; ++ci) {
        const float wv = WT[(size_t)ci * CIN + co];
        const float4 y0 = *(const float4*)&yl[ci][0];
        const float4 y1 = *(const float4*)&yl[ci][4];
        const float4 y2 = *(const float4*)&yl[ci][8];
        const float4 y3 = *(const float4*)&yl[ci][12];
        acc[0]  = __builtin_fmaf(wv, y0.x, acc[0]);
        acc[1]  = __builtin_fmaf(wv, y0.y, acc[1]);
        acc[2]  = __builtin_fmaf(wv, y0.z, acc[2]);
        acc[3]  = __builtin_fmaf(wv, y0.w, acc[3]);
        acc[4]  = __builtin_fmaf(wv, y1.x, acc[4]);
        acc[5]  = __builtin_fmaf(wv, y1.y, acc[5]);
        acc[6]  = __builtin_fmaf(wv, y1.z, acc[6]);
        acc[7]  = __builtin_fmaf(wv, y1.w, acc[7]);
        acc[8]  = __builtin_fmaf(wv, y2.x, acc[8]);
        acc[9]  = __builtin_fmaf(wv, y2.y, acc[9]);
        acc[10] = __builtin_fmaf(wv, y2.z, acc[10]);
        acc[11] = __builtin_fmaf(wv, y2.w, acc[11]);
        acc[12] = __builtin_fmaf(wv, y3.x, acc[12]);
        acc[13] = __builtin_fmaf(wv, y3.y, acc[13]);
        acc[14] = __builtin_fmaf(wv, y3.z, acc[14]);
        acc[15] = __builtin_fmaf(wv, y3.w, acc[15]);
    }
    const float wb = Wbias[co];
    const size_t ob = ((size_t)b * CIN + co) * NHW + n0;
    #pragma unroll
    for (int q = 0; q < 4; ++q) {
        float4 xv = *(const float4*)&x[ob + q*4];
        float4 ov;
        ov.x = acc[q*4+0] + xv.x + wb;
        ov.y = acc[q*4+1] + xv.y + wb;
        ov.z = acc[q*4+2] + xv.z + wb;
        ov.w = acc[q*4+3] + xv.w + wb;
        *(float4*)&out[ob + q*4] = ov;
    }
}

extern "C" void kernel_launch(void* const* d_in, const int* in_sizes, int n_in,
                              void* d_out, int out_size, void* d_ws, size_t ws_size,
                              hipStream_t stream)
{
    const float* x     = (const float*)d_in[0];
    const float* gw    = (const float*)d_in[1];
    const float* gbias = (const float*)d_in[2];
    const float* tw    = (const float*)d_in[3];
    const float* tbias = (const float*)d_in[4];
    const float* pw    = (const float*)d_in[5];
    const float* pbias = (const float*)d_in[6];
    const float* Ww    = (const float*)d_in[7];
    const float* Wbias = (const float*)d_in[8];

    // theta/phi split planes live in d_out (scratch until k_out rewrites it):
    // 4 x 3,276,800 B == out bytes (13,107,200) exactly.
    char* ob = (char*)d_out;
    const size_t SZ = (size_t)NB * NHW * CIO * 2;   // 3,276,800 B
    unsigned short* th_hi = (unsigned short*)(ob);
    unsigned short* th_lo = (unsigned short*)(ob + SZ);
    unsigned short* ph_hi = (unsigned short*)(ob + 2*SZ);
    unsigned short* ph_lo = (unsigned short*)(ob + 3*SZ);

    // ws: 13,158,400 B total (same footprint that passed in round 5)
    char* ws = (char*)d_ws;
    const size_t SZF = (size_t)NB * NHW * CIO * 4;   // 6,553,600 B
    float* g32 = (float*)(ws);               // dead after k_attn
    float* WT  = (float*)(ws);               // overlays g32 (written by k_wT after k_attn)
    float* yT  = (float*)(ws + SZF);
    float* Zp  = (float*)(ws + 2*SZF);       // 51,200 B
    float* out = (float*)d_out;

    k_zero  <<<dim3(50),     256, 0, stream>>>(Zp);
    k_proj  <<<dim3(400, 2), 256, 0, stream>>>(x, gw, gbias, tw, tbias, pw, pbias,
                                               th_hi, th_lo, ph_hi, ph_lo, g32);
    k_colsum<<<dim3(400, 2), 256, 0, stream>>>(ph_hi, ph_lo, th_hi, th_lo, Zp);
    k_attn  <<<dim3(400, 2), 256, 0, stream>>>(ph_hi, ph_lo, th_hi, th_lo, g32, Zp, yT);
    k_wT    <<<dim3(128),    256, 0, stream>>>(Ww, WT);
    k_out   <<<dim3(400, 2), 256, 0, stream>>>(yT, WT, Wbias, x, out);
}